// Round 9
// baseline (72.916 us; speedup 1.0000x reference)
//
#include <hip/hip_runtime.h>
#include <math.h>

// Shapes: x:(64,196,768) f32, ln_w/ln_b:(768,), sw/sb:(196,2,196), dw:(196,2)
//   W[o,n] = sum_m dw[o,m]*sw[o,m,n];  c[o] = sum_m dw[o,m]*sum_n sb[o,m,n]
//   t[b,o,d] = ln_w[d]*sum_n W[o,n]*xh[b,n,d] + ln_b[d]*rowsum[o] + c[o]
//   out[b,o,d] = x[b,o,d] * (gelu_erf(t) + 1)
// bf16 split MFMA: acc += Whi*Bhi + Whi*Blo + Wlo*Bhi (lo*lo dropped).
// R9: 16-wave blocks (wave-tile 16o x 64d, acc=16 VGPR), launch_bounds(1024,8)
// => 32 waves/CU; K pipelined in chunks {64,64,64,32} with double-buffered
// 2x16KB LDS; stage-loads issue one chunk early (T14); rolling A prefetch.

#define B_   64
#define N_   196
#define D_   768
#define KP   256

typedef __attribute__((ext_vector_type(8))) short bf16x8;
typedef __attribute__((ext_vector_type(4))) float f32x4;

__device__ __forceinline__ unsigned short bf16_rne(float f) {
    unsigned u = __builtin_bit_cast(unsigned, f);
    u += 0x7FFFu + ((u >> 16) & 1u);
    return (unsigned short)(u >> 16);
}
__device__ __forceinline__ float bf16_to_f(unsigned short h) {
    unsigned u = ((unsigned)h) << 16;
    return __builtin_bit_cast(float, u);
}

__global__ void prep_w_kernel(const float* __restrict__ sw,
                              const float* __restrict__ sb,
                              const float* __restrict__ dw,
                              unsigned short* __restrict__ Whi,
                              unsigned short* __restrict__ Wlo,
                              float* __restrict__ rowsum,
                              float* __restrict__ cvec) {
    int o = blockIdx.x;   // 0..255 (>=196 zero pad rows)
    int t = threadIdx.x;  // 0..255
    float w0 = 0.f, w1 = 0.f;
    if (o < N_) { w0 = dw[o * 2 + 0]; w1 = dw[o * 2 + 1]; }
    float val = 0.f, sbp = 0.f;
    if (o < N_ && t < N_) {
        val = w0 * sw[(o * 2 + 0) * N_ + t] + w1 * sw[(o * 2 + 1) * N_ + t];
        sbp = w0 * sb[(o * 2 + 0) * N_ + t] + w1 * sb[(o * 2 + 1) * N_ + t];
    }
    unsigned short h = bf16_rne(val);
    Whi[o * KP + t] = h;
    Wlo[o * KP + t] = bf16_rne(val - bf16_to_f(h));
    __shared__ float r1[256], r2[256];
    r1[t] = val; r2[t] = sbp;
    __syncthreads();
    for (int s = 128; s > 0; s >>= 1) {
        if (t < s) { r1[t] += r1[t + s]; r2[t] += r2[t + s]; }
        __syncthreads();
    }
    if (t == 0) { rowsum[o] = r1[0]; cvec[o] = r2[0]; }
}

__global__ void ln_stats_kernel(const float* __restrict__ x,
                                float* __restrict__ mu,
                                float* __restrict__ rstd) {
    int wave = threadIdx.x >> 6;
    int lane = threadIdx.x & 63;
    int row  = blockIdx.x * 4 + wave;
    const float4* xr = reinterpret_cast<const float4*>(x + (size_t)row * D_);
    float4 v0 = xr[lane];
    float4 v1 = xr[lane + 64];
    float4 v2 = xr[lane + 128];
    float s = v0.x + v0.y + v0.z + v0.w
            + v1.x + v1.y + v1.z + v1.w
            + v2.x + v2.y + v2.z + v2.w;
    #pragma unroll
    for (int off = 32; off >= 1; off >>= 1) s += __shfl_xor(s, off);
    float m = s * (1.0f / D_);
    float q = 0.f;
    {
        float d;
        d = v0.x - m; q += d * d;  d = v0.y - m; q += d * d;
        d = v0.z - m; q += d * d;  d = v0.w - m; q += d * d;
        d = v1.x - m; q += d * d;  d = v1.y - m; q += d * d;
        d = v1.z - m; q += d * d;  d = v1.w - m; q += d * d;
        d = v2.x - m; q += d * d;  d = v2.y - m; q += d * d;
        d = v2.z - m; q += d * d;  d = v2.w - m; q += d * d;
    }
    #pragma unroll
    for (int off = 32; off >= 1; off >>= 1) q += __shfl_xor(q, off);
    if (lane == 0) {
        mu[row]   = m;
        rstd[row] = rsqrtf(q * (1.0f / D_) + 1e-5f);
    }
}

// Grid: (12 d-tiles, 64 b), 1024 threads = 16 waves.
// Wave w: o-rows [w*16, w*16+16), full 64 d (4 nf frags), acc = 4 x f32x4.
// K chunks: kq pairs {0,1}{2,3}{4,5}{6}; chunk c in LDS buf[c&1] (8KB/arr).
// LDS addr swizzle: byte ^= (koct&3)<<5 (2-way max on b128 frag reads).
__global__ __launch_bounds__(1024, 8) void gemm_mfma_kernel(
    const float* __restrict__ x,
    const float* __restrict__ ln_w,
    const float* __restrict__ ln_b,
    const unsigned short* __restrict__ Whi,
    const unsigned short* __restrict__ Wlo,
    const float* __restrict__ rowsum,
    const float* __restrict__ cvec,
    const float* __restrict__ mu,
    const float* __restrict__ rstd,
    float* __restrict__ out) {
    const int b  = blockIdx.y;
    const int d0 = blockIdx.x * 64;
    const int t = threadIdx.x;
    const int w = t >> 6, lane = t & 63;
    const int m16 = lane & 15, g = lane >> 4;

    __shared__ __align__(16) unsigned short BsH[2][4096];  // [koct8][d64][k8]
    __shared__ __align__(16) unsigned short BsL[2][4096];

    const float* xb  = x + (size_t)b * (N_ * D_);
    const float* mub = mu + b * N_;
    const float* rsb = rstd + b * N_;

    // per-thread staging slice: k = c*64 + w*4 + e, d = lane
    float xv[4];
    float mus[4], rss[4];

    auto stage_load = [&](int c) {
        #pragma unroll
        for (int e = 0; e < 4; ++e) {
            const int k = c * 64 + w * 4 + e;
            if (k < N_) {
                xv[e]  = xb[(size_t)k * D_ + d0 + lane];
                mus[e] = mub[k];
                rss[e] = rsb[k];
            } else {
                xv[e] = 0.f; mus[e] = 0.f; rss[e] = 0.f;
            }
        }
    };
    auto stage_write = [&](int buf, int c) {
        if (c == 3 && w >= 8) return;   // chunk3: only kocts 0..3 are read
        const int kl0  = w * 4;
        const int koct = kl0 >> 3;
        short4 hv, lv;
        short* hp = &hv.x; short* lp = &lv.x;
        #pragma unroll
        for (int e = 0; e < 4; ++e) {
            float v = (xv[e] - mus[e]) * rss[e];
            unsigned short h = bf16_rne(v);
            hp[e] = (short)h;
            lp[e] = (short)bf16_rne(v - bf16_to_f(h));
        }
        const int byte = (((koct * 64 + lane) * 8 + (kl0 & 7)) * 2) ^ ((koct & 3) << 5);
        *reinterpret_cast<short4*>(reinterpret_cast<char*>(BsH[buf]) + byte) = hv;
        *reinterpret_cast<short4*>(reinterpret_cast<char*>(BsL[buf]) + byte) = lv;
    };

    // ---- prologue: chunk 0 ----
    stage_load(0);
    stage_write(0, 0);
    __syncthreads();

    f32x4 acc[4];
    #pragma unroll
    for (int j = 0; j < 4; ++j) acc[j] = (f32x4){0.f, 0.f, 0.f, 0.f};

    const int arow = (w * 16 + m16) * KP;   // o-row in padded W
    bf16x8 ah, al, ahn, aln;
    ah = *reinterpret_cast<const bf16x8*>(Whi + arow + g * 8);
    al = *reinterpret_cast<const bf16x8*>(Wlo + arow + g * 8);

    #pragma unroll
    for (int kq = 0; kq < 7; ++kq) {
        const int c = kq >> 1, buf = c & 1;
        if (kq < 6) {
            const int col = (kq + 1) * 32 + g * 8;
            ahn = *reinterpret_cast<const bf16x8*>(Whi + arow + col);
            aln = *reinterpret_cast<const bf16x8*>(Wlo + arow + col);
        }
        if ((kq & 1) == 0 && c < 3) stage_load(c + 1);  // issue early (T14)
        #pragma unroll
        for (int nf = 0; nf < 4; ++nf) {
            const int koct = (kq & 1) * 4 + g;
            const int byte = ((koct * 64 + nf * 16 + m16) * 16) ^ ((koct & 3) << 5);
            bf16x8 bh = *reinterpret_cast<const bf16x8*>(
                reinterpret_cast<const char*>(BsH[buf]) + byte);
            bf16x8 bl = *reinterpret_cast<const bf16x8*>(
                reinterpret_cast<const char*>(BsL[buf]) + byte);
            acc[nf] = __builtin_amdgcn_mfma_f32_16x16x32_bf16(ah, bh, acc[nf], 0, 0, 0);
            acc[nf] = __builtin_amdgcn_mfma_f32_16x16x32_bf16(ah, bl, acc[nf], 0, 0, 0);
            acc[nf] = __builtin_amdgcn_mfma_f32_16x16x32_bf16(al, bh, acc[nf], 0, 0, 0);
        }
        if ((kq & 1) == 1 && c < 3) {
            __syncthreads();                 // all waves done reading buf[(c+1)&1]
            stage_write((c + 1) & 1, c + 1); // write next chunk
            __syncthreads();
        }
        ah = ahn; al = aln;
    }

    // ---- epilogue ----
    // C/D layout: col(d) = lane&15, row(o) = (lane>>4)*4 + reg
    float lwv[4], lbv[4];
    #pragma unroll
    for (int nf = 0; nf < 4; ++nf) {
        lwv[nf] = ln_w[d0 + nf * 16 + m16];
        lbv[nf] = ln_b[d0 + nf * 16 + m16];
    }
    #pragma unroll
    for (int r = 0; r < 4; ++r) {
        const int o = w * 16 + g * 4 + r;
        if (o < N_) {
            const float rs = rowsum[o], cc = cvec[o];
            #pragma unroll
            for (int nf = 0; nf < 4; ++nf) {
                const int d = d0 + nf * 16 + m16;
                float T = fmaf(lwv[nf], acc[nf][r], fmaf(lbv[nf], rs, cc));
                float gl = 0.5f * T * (1.0f + erff(T * 0.70710678118654752f));
                out[((size_t)(b * N_ + o)) * D_ + d] = xb[(size_t)o * D_ + d] * (gl + 1.0f);
            }
        }
    }
}

extern "C" void kernel_launch(void* const* d_in, const int* in_sizes, int n_in,
                              void* d_out, int out_size, void* d_ws, size_t ws_size,
                              hipStream_t stream) {
    const float* x    = (const float*)d_in[0];
    const float* ln_w = (const float*)d_in[1];
    const float* ln_b = (const float*)d_in[2];
    const float* sw   = (const float*)d_in[3];
    const float* sb   = (const float*)d_in[4];
    const float* dw   = (const float*)d_in[5];
    float* out = (float*)d_out;

    float* wsf = (float*)d_ws;
    float* mu     = wsf;                       // 12544 f32
    float* rstd   = mu + B_ * N_;              // 12544 f32
    float* rowsum = rstd + B_ * N_;            // 256 f32
    float* cvec   = rowsum + KP;               // 256 f32
    unsigned short* Whi = (unsigned short*)(cvec + KP);    // 256*256 u16
    unsigned short* Wlo = Whi + KP * KP;                   // 256*256 u16

    prep_w_kernel<<<KP, 256, 0, stream>>>(sw, sb, dw, Whi, Wlo, rowsum, cvec);
    ln_stats_kernel<<<(B_ * N_) / 4, 256, 0, stream>>>(x, mu, rstd);
    gemm_mfma_kernel<<<dim3(12, B_), 1024, 0, stream>>>(
        x, ln_w, ln_b, Whi, Wlo, rowsum, cvec, mu, rstd, out);
}

// Round 10
// 54.822 us; speedup vs baseline: 1.3301x; 1.3301x over previous
//
#include <hip/hip_runtime.h>
#include <math.h>

// Shapes: x:(64,196,768) f32, ln_w/ln_b:(768,), sw/sb:(196,2,196), dw:(196,2)
//   W[o,n] = sum_m dw[o,m]*sw[o,m,n];  c[o] = sum_m dw[o,m]*sum_n sb[o,m,n]
//   t[b,o,d] = ln_w[d]*sum_n W[o,n]*xh[b,n,d] + ln_b[d]*rowsum[o] + c[o]
//   out[b,o,d] = x[b,o,d] * (gelu_erf(t) + 1)
// bf16 split MFMA: acc += Whi*Bhi + Whi*Blo + Wlo*Bhi (lo*lo dropped).
// R10: fix R9's scratch spill (VGPR=32 cap -> 71MB spill writes). 512 thr /
// 8 waves, launch_bounds(512,4) (128 VGPR cap, ~110 used, no spill).
// One barrier per 32-k chunk: write(c); sync; load(c+2); MFMA(c).
// W pre-packed in fragment order so A-loads are contiguous 1KB wave-loads.

#define B_   64
#define N_   196
#define D_   768
#define KQ   7     // 7 chunks of 32 k = 224 (padded)
#define OPAD 256

typedef __attribute__((ext_vector_type(8))) short bf16x8;
typedef __attribute__((ext_vector_type(4))) float f32x4;

__device__ __forceinline__ unsigned short bf16_rne(float f) {
    unsigned u = __builtin_bit_cast(unsigned, f);
    u += 0x7FFFu + ((u >> 16) & 1u);
    return (unsigned short)(u >> 16);
}
__device__ __forceinline__ float bf16_to_f(unsigned short h) {
    unsigned u = ((unsigned)h) << 16;
    return __builtin_bit_cast(float, u);
}

// Wfh/Wfl frag-packed: [otile(o>>4)][kq(k>>5)][g((k>>3)&3)][m16(o&15)][k&7]
__global__ void prep_w_kernel(const float* __restrict__ sw,
                              const float* __restrict__ sb,
                              const float* __restrict__ dw,
                              unsigned short* __restrict__ Wfh,
                              unsigned short* __restrict__ Wfl,
                              float* __restrict__ rowsum,
                              float* __restrict__ cvec) {
    int o = blockIdx.x;   // 0..255 (>=196 zero rows)
    int t = threadIdx.x;  // 0..255 (k index; only t<224 stored)
    float w0 = 0.f, w1 = 0.f;
    if (o < N_) { w0 = dw[o * 2 + 0]; w1 = dw[o * 2 + 1]; }
    float val = 0.f, sbp = 0.f;
    if (o < N_ && t < N_) {
        val = w0 * sw[(o * 2 + 0) * N_ + t] + w1 * sw[(o * 2 + 1) * N_ + t];
        sbp = w0 * sb[(o * 2 + 0) * N_ + t] + w1 * sb[(o * 2 + 1) * N_ + t];
    }
    if (t < KQ * 32) {
        unsigned short h = bf16_rne(val);
        int addr = ((((o >> 4) * KQ + (t >> 5)) * 4 + ((t >> 3) & 3)) * 16 + (o & 15)) * 8 + (t & 7);
        Wfh[addr] = h;
        Wfl[addr] = bf16_rne(val - bf16_to_f(h));
    }
    __shared__ float r1[256], r2[256];
    r1[t] = val; r2[t] = sbp;
    __syncthreads();
    for (int s = 128; s > 0; s >>= 1) {
        if (t < s) { r1[t] += r1[t + s]; r2[t] += r2[t + s]; }
        __syncthreads();
    }
    if (t == 0) { rowsum[o] = r1[0]; cvec[o] = r2[0]; }
}

__global__ void ln_stats_kernel(const float* __restrict__ x,
                                float* __restrict__ mu,
                                float* __restrict__ rstd) {
    int wave = threadIdx.x >> 6;
    int lane = threadIdx.x & 63;
    int row  = blockIdx.x * 4 + wave;
    const float4* xr = reinterpret_cast<const float4*>(x + (size_t)row * D_);
    float4 v0 = xr[lane];
    float4 v1 = xr[lane + 64];
    float4 v2 = xr[lane + 128];
    float s = v0.x + v0.y + v0.z + v0.w
            + v1.x + v1.y + v1.z + v1.w
            + v2.x + v2.y + v2.z + v2.w;
    #pragma unroll
    for (int off = 32; off >= 1; off >>= 1) s += __shfl_xor(s, off);
    float m = s * (1.0f / D_);
    float q = 0.f;
    {
        float d;
        d = v0.x - m; q += d * d;  d = v0.y - m; q += d * d;
        d = v0.z - m; q += d * d;  d = v0.w - m; q += d * d;
        d = v1.x - m; q += d * d;  d = v1.y - m; q += d * d;
        d = v1.z - m; q += d * d;  d = v1.w - m; q += d * d;
        d = v2.x - m; q += d * d;  d = v2.y - m; q += d * d;
        d = v2.z - m; q += d * d;  d = v2.w - m; q += d * d;
    }
    #pragma unroll
    for (int off = 32; off >= 1; off >>= 1) q += __shfl_xor(q, off);
    if (lane == 0) {
        mu[row]   = m;
        rstd[row] = rsqrtf(q * (1.0f / D_) + 1e-5f);
    }
}

// Grid (12 d-tiles, 64 b), 512 threads = 8 waves.
// Wave w: o-rows [w*32, w*32+32) (2 mf) x 64 d (4 nf); acc = 8 x f32x4.
// LDS: double-buffered chunk tiles [koct4][d64][k8] bf16, hi+lo = 16KB.
// Per chunk c: {write(c); sync; load(c+2); prefetch A(c+1); 24 MFMA on c}.

#define LOADC(s, c) do {                                                      \
    _Pragma("unroll")                                                         \
    for (int e = 0; e < 4; ++e) {                                             \
        const int k = (c) * 32 + w * 4 + e;                                   \
        if (k < N_) {                                                         \
            xv[s][e]  = xb[(size_t)k * D_ + d0 + lane];                       \
            mus[s][e] = mub[k];                                               \
            rss[s][e] = rsb[k];                                               \
        } else { xv[s][e] = 0.f; mus[s][e] = 0.f; rss[s][e] = 0.f; }          \
    } } while (0)

#define WRITEC(s) do {                                                        \
    short4 hv, lv; short* hp = &hv.x; short* lp = &lv.x;                      \
    _Pragma("unroll")                                                         \
    for (int e = 0; e < 4; ++e) {                                             \
        float v = (xv[s][e] - mus[s][e]) * rss[s][e];                         \
        unsigned short h = bf16_rne(v);                                       \
        hp[e] = (short)h;                                                     \
        lp[e] = (short)bf16_rne(v - bf16_to_f(h));                            \
    }                                                                         \
    const int ea = ((w >> 1) * 64 + lane) * 8 + (w & 1) * 4;                  \
    *reinterpret_cast<short4*>(&BsH[s][ea]) = hv;                             \
    *reinterpret_cast<short4*>(&BsL[s][ea]) = lv; } while (0)

#define LOADA(slot, c) do {                                                   \
    _Pragma("unroll")                                                         \
    for (int mf = 0; mf < 2; ++mf) {                                          \
        const size_t ab = ((size_t)((w * 2 + mf) * KQ + (c)) * 512) + lane * 8;\
        ah[slot][mf] = *reinterpret_cast<const bf16x8*>(Wfh + ab);            \
        al[slot][mf] = *reinterpret_cast<const bf16x8*>(Wfl + ab);            \
    } } while (0)

__global__ __launch_bounds__(512, 4) void gemm_mfma_kernel(
    const float* __restrict__ x,
    const float* __restrict__ ln_w,
    const float* __restrict__ ln_b,
    const unsigned short* __restrict__ Wfh,
    const unsigned short* __restrict__ Wfl,
    const float* __restrict__ rowsum,
    const float* __restrict__ cvec,
    const float* __restrict__ mu,
    const float* __restrict__ rstd,
    float* __restrict__ out) {
    const int b  = blockIdx.y;
    const int d0 = blockIdx.x * 64;
    const int t = threadIdx.x;
    const int w = t >> 6, lane = t & 63;
    const int m16 = lane & 15, g = lane >> 4;

    __shared__ __align__(16) unsigned short BsH[2][2048];  // [buf][koct4][d64][k8]
    __shared__ __align__(16) unsigned short BsL[2][2048];

    const float* xb  = x + (size_t)b * (N_ * D_);
    const float* mub = mu + b * N_;
    const float* rsb = rstd + b * N_;

    float xv[2][4], mus[2][4], rss[2][4];
    bf16x8 ah[2][2], al[2][2];

    f32x4 acc[2][4];
    #pragma unroll
    for (int i = 0; i < 2; ++i)
        #pragma unroll
        for (int j = 0; j < 4; ++j)
            acc[i][j] = (f32x4){0.f, 0.f, 0.f, 0.f};

    // ---- prologue: chunks 0,1 in flight; A(0); write chunk 0 ----
    LOADC(0, 0);
    LOADC(1, 1);
    LOADA(0, 0);
    WRITEC(0);
    __syncthreads();

    #pragma unroll
    for (int c = 0; c < KQ; ++c) {
        const int s = c & 1;
        if (c > 0) {
            WRITEC(s);
            __syncthreads();
        }
        if (c + 2 < KQ) LOADC(s, c + 2);
        if (c + 1 < KQ) LOADA((c + 1) & 1, c + 1);
        #pragma unroll
        for (int nf = 0; nf < 4; ++nf) {
            const int ba = (g * 64 + nf * 16 + m16) * 8;
            bf16x8 bh = *reinterpret_cast<const bf16x8*>(&BsH[s][ba]);
            bf16x8 bl = *reinterpret_cast<const bf16x8*>(&BsL[s][ba]);
            #pragma unroll
            for (int mf = 0; mf < 2; ++mf) {
                acc[mf][nf] = __builtin_amdgcn_mfma_f32_16x16x32_bf16(ah[s][mf], bh, acc[mf][nf], 0, 0, 0);
                acc[mf][nf] = __builtin_amdgcn_mfma_f32_16x16x32_bf16(ah[s][mf], bl, acc[mf][nf], 0, 0, 0);
                acc[mf][nf] = __builtin_amdgcn_mfma_f32_16x16x32_bf16(al[s][mf], bh, acc[mf][nf], 0, 0, 0);
            }
        }
    }

    // ---- epilogue: T = lnw*acc + lnb*rowsum + c; out = x*(gelu(T)+1) ----
    // C/D layout: col(d) = lane&15, row(o) = (lane>>4)*4 + reg
    float lwv[4], lbv[4];
    #pragma unroll
    for (int nf = 0; nf < 4; ++nf) {
        lwv[nf] = ln_w[d0 + nf * 16 + m16];
        lbv[nf] = ln_b[d0 + nf * 16 + m16];
    }
    #pragma unroll
    for (int mf = 0; mf < 2; ++mf) {
        #pragma unroll
        for (int r = 0; r < 4; ++r) {
            const int o = w * 32 + mf * 16 + g * 4 + r;
            if (o < N_) {
                const float rs = rowsum[o], cc = cvec[o];
                #pragma unroll
                for (int nf = 0; nf < 4; ++nf) {
                    const int d = d0 + nf * 16 + m16;
                    float T = fmaf(lwv[nf], acc[mf][nf][r], fmaf(lbv[nf], rs, cc));
                    float gl = 0.5f * T * (1.0f + erff(T * 0.70710678118654752f));
                    out[((size_t)(b * N_ + o)) * D_ + d] = xb[(size_t)o * D_ + d] * (gl + 1.0f);
                }
            }
        }
    }
}

extern "C" void kernel_launch(void* const* d_in, const int* in_sizes, int n_in,
                              void* d_out, int out_size, void* d_ws, size_t ws_size,
                              hipStream_t stream) {
    const float* x    = (const float*)d_in[0];
    const float* ln_w = (const float*)d_in[1];
    const float* ln_b = (const float*)d_in[2];
    const float* sw   = (const float*)d_in[3];
    const float* sb   = (const float*)d_in[4];
    const float* dw   = (const float*)d_in[5];
    float* out = (float*)d_out;

    float* wsf = (float*)d_ws;
    float* mu     = wsf;                       // 12544 f32
    float* rstd   = mu + B_ * N_;              // 12544 f32
    float* rowsum = rstd + B_ * N_;            // 256 f32
    float* cvec   = rowsum + OPAD;             // 256 f32
    unsigned short* Wfh = (unsigned short*)(cvec + OPAD);  // 256*224 u16
    unsigned short* Wfl = Wfh + OPAD * (KQ * 32);          // 256*224 u16

    prep_w_kernel<<<OPAD, 256, 0, stream>>>(sw, sb, dw, Wfh, Wfl, rowsum, cvec);
    ln_stats_kernel<<<(B_ * N_) / 4, 256, 0, stream>>>(x, mu, rstd);
    gemm_mfma_kernel<<<dim3(12, B_), 512, 0, stream>>>(
        x, ln_w, ln_b, Wfh, Wfl, rowsum, cvec, mu, rstd, out);
}